// Round 7
// baseline (347.419 us; speedup 1.0000x reference)
//
#include <hip/hip_runtime.h>
#include <math.h>

#define NROWS 4096
#define DDIM  1024

typedef __attribute__((ext_vector_type(8))) short short8;
typedef __attribute__((ext_vector_type(4))) float f32x4;

// ---------- bf16 helpers (manual RNE) ----------
__device__ __forceinline__ ushort f2bf(float v) {
  union { float f; uint32_t u; } c; c.f = v;
  uint32_t u = c.u;
  uint32_t lsb = (u >> 16) & 1u;
  u += 0x7fffu + lsb;
  return (ushort)(u >> 16);
}
__device__ __forceinline__ float bf2f(ushort h) {
  union { uint32_t u; float f; } c; c.u = ((uint32_t)h) << 16;
  return c.f;
}

// ---------- packed-fragment layout ----------
// Matrix [R][C] bf16 as 16x32 tiles of 1KB: tile T = (r>>4)*ldt + (c>>5), ldt=C/32.
// In-tile ushort index = ((c>>3)&3)*128 + (r&15)*8 + (c&7).
// Lane ln reads 16B at T*512 + ln*8 -> holds r=ln&15, c=(ln>>4)*8+j : exactly the
// 16x16x32 MFMA A-frag (m,k) and B-frag (n,k). Same layout serves both operands.
__device__ __forceinline__ size_t pidx(int r, int c, int ldt) {
  return ((size_t)((r >> 4) * ldt + (c >> 5))) * 512 +
         ((c >> 3) & 3) * 128 + (r & 15) * 8 + (c & 7);
}

// ---------- prep: split x + transpose/split 3 weights, ALL outputs packed ----------
__global__ __launch_bounds__(256) void prep(const float* __restrict__ x,
                                            const float* __restrict__ wq,
                                            const float* __restrict__ wk,
                                            const float* __restrict__ wv,
                                            ushort* Xh, ushort* Xl,
                                            ushort* Wqh, ushort* Wql,
                                            ushort* Wkh, ushort* Wkl, ushort* Wvh) {
  __shared__ float tl[32][33];
  const int b = blockIdx.x, t = threadIdx.x;
  if (b < 1024) {
    const float4* src = (const float4*)x;
#pragma unroll
    for (int r = 0; r < 4; ++r) {
      int i = b * 1024 + r * 256 + t;      // float4 index
      int row = i >> 8;                    // 256 float4 per row
      int c = (i & 255) * 4;               // col, multiple of 4 (8B-aligned in tile)
      float4 v = src[i];
      ushort4 h, l;
      h.x = f2bf(v.x); l.x = f2bf(v.x - bf2f(h.x));
      h.y = f2bf(v.y); l.y = f2bf(v.y - bf2f(h.y));
      h.z = f2bf(v.z); l.z = f2bf(v.z - bf2f(h.z));
      h.w = f2bf(v.w); l.w = f2bf(v.w - bf2f(h.w));
      size_t o = pidx(row, c, DDIM / 32);
      *(ushort4*)(Xh + o) = h;
      *(ushort4*)(Xl + o) = l;
    }
  } else {
    const int z = (b - 1024) >> 10;
    const int tile = (b - 1024) & 1023;
    const float* src = z == 0 ? wq : (z == 1 ? wk : wv);
    ushort* dh = z == 0 ? Wqh : (z == 1 ? Wkh : Wvh);
    ushort* dl = z == 0 ? Wql : (z == 1 ? Wkl : nullptr);
    const int r0 = (tile >> 5) * 32;       // k block
    const int c0 = (tile & 31) * 32;       // n block
    const int tx = t & 31, ty = t >> 5;
    for (int i = ty; i < 32; i += 8)
      tl[i][tx] = src[(size_t)(r0 + i) * DDIM + c0 + tx];
    __syncthreads();
    for (int i = ty; i < 32; i += 8) {
      float v = tl[tx][i];                 // = src[r0+tx][c0+i] -> W^T[c0+i][r0+tx]
      ushort h = f2bf(v);
      size_t o = pidx(c0 + i, r0 + tx, DDIM / 32);
      dh[o] = h;
      if (dl) dl[o] = f2bf(v - bf2f(h));
    }
  }
}

// ---------- fused QKV, LDS-free, packed in/out ----------
// which = bx%3: 0->Q (split), 1->K (split), 2->Vt (plain, computed transposed)
__global__ __launch_bounds__(256) void gemm_qkv(const ushort* __restrict__ Xh,
                                                const ushort* __restrict__ Xl,
                                                const ushort* __restrict__ Wqh, const ushort* __restrict__ Wql,
                                                const ushort* __restrict__ Wkh, const ushort* __restrict__ Wkl,
                                                const ushort* __restrict__ Wvh,
                                                ushort* Qh, ushort* Ql, ushort* Kh, ushort* Kl, ushort* Vt) {
  const int which = blockIdx.x % 3;
  const int g = blockIdx.x / 3;            // 0..7
  const int t = threadIdx.x;
  const int wv = t >> 6, ln = t & 63;
  const int quad = ln >> 4, l16 = ln & 15;
  const int arb = (wv >> 1) * 64, crb = (wv & 1) * 64;

  f32x4 acc[4][4];
#pragma unroll
  for (int i = 0; i < 4; ++i)
#pragma unroll
    for (int j = 0; j < 4; ++j) acc[i][j] = (f32x4){0.f, 0.f, 0.f, 0.f};

  if (which == 2) {
    // Vt[d][kv] = sum_k Wvh[d][k]*Xh[kv][k]; A=Wvh (1024 rows), B=Xh (4096 rows)
    const int m0 = g * 128, n0 = blockIdx.y * 128;
    size_t baseA[4], baseB[4];
#pragma unroll
    for (int i = 0; i < 4; ++i) baseA[i] = (size_t)(((m0 + arb) >> 4) + i) * 16384 + ln * 8;
#pragma unroll
    for (int j = 0; j < 4; ++j) baseB[j] = (size_t)(((n0 + crb) >> 4) + j) * 16384 + ln * 8;
#pragma unroll 2
    for (int s = 0; s < 32; ++s) {
      short8 a[4], bb[4];
#pragma unroll
      for (int i = 0; i < 4; ++i) a[i] = *(const short8*)(Wvh + baseA[i] + (size_t)s * 512);
#pragma unroll
      for (int j = 0; j < 4; ++j) bb[j] = *(const short8*)(Xh + baseB[j] + (size_t)s * 512);
#pragma unroll
      for (int i = 0; i < 4; ++i)
#pragma unroll
        for (int j = 0; j < 4; ++j)
          acc[i][j] = __builtin_amdgcn_mfma_f32_16x16x32_bf16(a[i], bb[j], acc[i][j], 0, 0, 0);
    }
#pragma unroll
    for (int i = 0; i < 4; ++i)
#pragma unroll
      for (int j = 0; j < 4; ++j) {
        int kv = n0 + crb + j * 16 + l16;
        int d = m0 + arb + i * 16 + quad * 4;
#pragma unroll
        for (int r2 = 0; r2 < 4; ++r2)
          Vt[pidx(d + r2, kv, NROWS / 32)] = f2bf(acc[i][j][r2]);
      }
  } else {
    const int m0 = blockIdx.y * 128, n0 = g * 128;
    const ushort* Bh = which ? Wkh : Wqh;
    const ushort* Bl = which ? Wkl : Wql;
    size_t baseA[4], baseB[4];
#pragma unroll
    for (int i = 0; i < 4; ++i) baseA[i] = (size_t)(((m0 + arb) >> 4) + i) * 16384 + ln * 8;
#pragma unroll
    for (int j = 0; j < 4; ++j) baseB[j] = (size_t)(((n0 + crb) >> 4) + j) * 16384 + ln * 8;
#pragma unroll 2
    for (int s = 0; s < 32; ++s) {
      short8 ah[4], al[4];
#pragma unroll
      for (int i = 0; i < 4; ++i) {
        size_t o = baseA[i] + (size_t)s * 512;
        ah[i] = *(const short8*)(Xh + o);
        al[i] = *(const short8*)(Xl + o);
      }
#pragma unroll
      for (int j = 0; j < 4; ++j) {
        size_t o = baseB[j] + (size_t)s * 512;
        short8 bh = *(const short8*)(Bh + o);
        short8 bl = *(const short8*)(Bl + o);
#pragma unroll
        for (int i = 0; i < 4; ++i) {
          acc[i][j] = __builtin_amdgcn_mfma_f32_16x16x32_bf16(ah[i], bh, acc[i][j], 0, 0, 0);
          acc[i][j] = __builtin_amdgcn_mfma_f32_16x16x32_bf16(ah[i], bl, acc[i][j], 0, 0, 0);
          acc[i][j] = __builtin_amdgcn_mfma_f32_16x16x32_bf16(al[i], bh, acc[i][j], 0, 0, 0);
        }
      }
    }
    const float scale = which ? 1.0f : 0.03125f;  // fold 1/sqrt(1024) into Q
    ushort* H = which ? Kh : Qh;
    ushort* L = which ? Kl : Ql;
#pragma unroll
    for (int i = 0; i < 4; ++i)
#pragma unroll
      for (int j = 0; j < 4; ++j) {
        int col = n0 + crb + j * 16 + l16;
        int rw = m0 + arb + i * 16 + quad * 4;
#pragma unroll
        for (int r2 = 0; r2 < 4; ++r2) {
          float v = acc[i][j][r2] * scale;
          ushort h = f2bf(v);
          size_t o = pidx(rw + r2, col, DDIM / 32);
          H[o] = h;
          L[o] = f2bf(v - bf2f(h));
        }
      }
  }
}

// ---------- S = Q*K^T (split), LDS-free, barrier-free ----------
__global__ __launch_bounds__(256) void gemm_s(const ushort* __restrict__ Qh, const ushort* __restrict__ Ql,
                                              const ushort* __restrict__ Kh, const ushort* __restrict__ Kl,
                                              float* __restrict__ S) {
  const int n0 = blockIdx.x * 128, m0 = blockIdx.y * 128;
  const int t = threadIdx.x;
  const int wv = t >> 6, ln = t & 63;
  const int quad = ln >> 4, l16 = ln & 15;
  const int arb = (wv >> 1) * 64, crb = (wv & 1) * 64;

  f32x4 acc[4][4];
#pragma unroll
  for (int i = 0; i < 4; ++i)
#pragma unroll
    for (int j = 0; j < 4; ++j) acc[i][j] = (f32x4){0.f, 0.f, 0.f, 0.f};

  size_t baseA[4], baseB[4];
#pragma unroll
  for (int i = 0; i < 4; ++i) baseA[i] = (size_t)(((m0 + arb) >> 4) + i) * 16384 + ln * 8;
#pragma unroll
  for (int j = 0; j < 4; ++j) baseB[j] = (size_t)(((n0 + crb) >> 4) + j) * 16384 + ln * 8;

#pragma unroll 2
  for (int s = 0; s < 32; ++s) {
    short8 ah[4], al[4];
#pragma unroll
    for (int i = 0; i < 4; ++i) {
      size_t o = baseA[i] + (size_t)s * 512;
      ah[i] = *(const short8*)(Qh + o);
      al[i] = *(const short8*)(Ql + o);
    }
#pragma unroll
    for (int j = 0; j < 4; ++j) {
      size_t o = baseB[j] + (size_t)s * 512;
      short8 bh = *(const short8*)(Kh + o);
      short8 bl = *(const short8*)(Kl + o);
#pragma unroll
      for (int i = 0; i < 4; ++i) {
        acc[i][j] = __builtin_amdgcn_mfma_f32_16x16x32_bf16(ah[i], bh, acc[i][j], 0, 0, 0);
        acc[i][j] = __builtin_amdgcn_mfma_f32_16x16x32_bf16(ah[i], bl, acc[i][j], 0, 0, 0);
        acc[i][j] = __builtin_amdgcn_mfma_f32_16x16x32_bf16(al[i], bh, acc[i][j], 0, 0, 0);
      }
    }
  }

#pragma unroll
  for (int i = 0; i < 4; ++i)
#pragma unroll
    for (int j = 0; j < 4; ++j) {
      int col = n0 + crb + j * 16 + l16;
      int rw = m0 + arb + i * 16 + quad * 4;
#pragma unroll
      for (int r2 = 0; r2 < 4; ++r2)
        S[(size_t)(rw + r2) * NROWS + col] = acc[i][j][r2];
    }
}

// ---------- softmax: row of S (fp32) -> PACKED bf16 P ----------
__global__ __launch_bounds__(256) void softmax_pack(const float* __restrict__ S,
                                                    ushort* __restrict__ P) {
  const int row = blockIdx.x, t = threadIdx.x;
  const float* Sr = S + (size_t)row * NROWS;
  const float4* S4 = (const float4*)Sr;
  float4 v[4];
  float mx = -3.4e38f;
#pragma unroll
  for (int c = 0; c < 4; ++c) {
    v[c] = S4[c * 256 + t];
    mx = fmaxf(mx, fmaxf(fmaxf(v[c].x, v[c].y), fmaxf(v[c].z, v[c].w)));
  }
  __shared__ float red[4];
  for (int o = 32; o >= 1; o >>= 1) mx = fmaxf(mx, __shfl_xor(mx, o));
  int wv = t >> 6, ln = t & 63;
  if (ln == 0) red[wv] = mx;
  __syncthreads();
  mx = fmaxf(fmaxf(red[0], red[1]), fmaxf(red[2], red[3]));
  float s = 0.f;
#pragma unroll
  for (int c = 0; c < 4; ++c) {
    v[c].x = __expf(v[c].x - mx);
    v[c].y = __expf(v[c].y - mx);
    v[c].z = __expf(v[c].z - mx);
    v[c].w = __expf(v[c].w - mx);
    s += v[c].x + v[c].y + v[c].z + v[c].w;
  }
  for (int o = 32; o >= 1; o >>= 1) s += __shfl_xor(s, o);
  __syncthreads();
  if (ln == 0) red[wv] = s;
  __syncthreads();
  s = red[0] + red[1] + red[2] + red[3];
  float inv = 1.f / s;
#pragma unroll
  for (int c = 0; c < 4; ++c) {
    ushort4 h;
    h.x = f2bf(v[c].x * inv);
    h.y = f2bf(v[c].y * inv);
    h.z = f2bf(v[c].z * inv);
    h.w = f2bf(v[c].w * inv);
    int c0 = 1024 * c + 4 * t;
    *(ushort4*)(P + pidx(row, c0, NROWS / 32)) = h;
  }
}

// ---------- Out_partial[z] = P*V over k-slice z; LDS-free, BM=128, split-K=2 ----------
__global__ __launch_bounds__(256) void gemm_pv(const ushort* __restrict__ P,
                                               const ushort* __restrict__ Vt,
                                               float* __restrict__ part) {
  const int n0 = blockIdx.x * 128, m0 = blockIdx.y * 128;
  const int kt0 = blockIdx.z * 64;         // tile offset within 128-tile K rows
  float* dst = part + (size_t)blockIdx.z * NROWS * DDIM;
  const int t = threadIdx.x;
  const int wv = t >> 6, ln = t & 63;
  const int quad = ln >> 4, l16 = ln & 15;
  const int arb = (wv >> 1) * 64, crb = (wv & 1) * 64;

  f32x4 acc[4][4];
#pragma unroll
  for (int i = 0; i < 4; ++i)
#pragma unroll
    for (int j = 0; j < 4; ++j) acc[i][j] = (f32x4){0.f, 0.f, 0.f, 0.f};

  size_t baseA[4], baseB[4];
#pragma unroll
  for (int i = 0; i < 4; ++i)
    baseA[i] = (size_t)(((m0 + arb) >> 4) + i) * 65536 + (size_t)kt0 * 512 + ln * 8;
#pragma unroll
  for (int j = 0; j < 4; ++j)
    baseB[j] = (size_t)(((n0 + crb) >> 4) + j) * 65536 + (size_t)kt0 * 512 + ln * 8;

#pragma unroll 2
  for (int s = 0; s < 64; ++s) {
    short8 a[4], bb[4];
#pragma unroll
    for (int i = 0; i < 4; ++i) a[i] = *(const short8*)(P + baseA[i] + (size_t)s * 512);
#pragma unroll
    for (int j = 0; j < 4; ++j) bb[j] = *(const short8*)(Vt + baseB[j] + (size_t)s * 512);
#pragma unroll
    for (int i = 0; i < 4; ++i)
#pragma unroll
      for (int j = 0; j < 4; ++j)
        acc[i][j] = __builtin_amdgcn_mfma_f32_16x16x32_bf16(a[i], bb[j], acc[i][j], 0, 0, 0);
  }

#pragma unroll
  for (int i = 0; i < 4; ++i)
#pragma unroll
    for (int j = 0; j < 4; ++j) {
      int col = n0 + crb + j * 16 + l16;
      int rw = m0 + arb + i * 16 + quad * 4;
#pragma unroll
      for (int r2 = 0; r2 < 4; ++r2)
        dst[(size_t)(rw + r2) * DDIM + col] = acc[i][j][r2];
    }
}

// ---------- Out = part0 + part1 ----------
__global__ __launch_bounds__(256) void add_partials(const float4* __restrict__ p0,
                                                    const float4* __restrict__ p1,
                                                    float4* __restrict__ out, int n4) {
  for (int i = blockIdx.x * 256 + threadIdx.x; i < n4; i += gridDim.x * 256) {
    float4 a = p0[i], b = p1[i];
    out[i] = (float4){a.x + b.x, a.y + b.y, a.z + b.z, a.w + b.w};
  }
}

extern "C" void kernel_launch(void* const* d_in, const int* in_sizes, int n_in,
                              void* d_out, int out_size, void* d_ws, size_t ws_size,
                              hipStream_t stream) {
  const float* x  = (const float*)d_in[0];
  const float* wq = (const float*)d_in[1];
  const float* wk = (const float*)d_in[2];
  const float* wv = (const float*)d_in[3];
  char* ws = (char*)d_ws;
  const size_t MB = 1u << 20;

  // Workspace map (peak 104 MiB), all matrices packed-fragment layout:
  ushort* Vt  = (ushort*)(ws + 0);        // 0-8   alive through pv
  ushort* Qh  = (ushort*)(ws + 8 * MB);   // 8-40  dead after gemm_s
  ushort* Ql  = (ushort*)(ws + 16 * MB);
  ushort* Kh  = (ushort*)(ws + 24 * MB);
  ushort* Kl  = (ushort*)(ws + 32 * MB);
  ushort* Pp  = (ushort*)(ws + 8 * MB);   // 8-40  packed P (aliases dead Q/K)
  ushort* Xh  = (ushort*)(ws + 40 * MB);  // 40-56 dead after qkv
  ushort* Xl  = (ushort*)(ws + 48 * MB);
  ushort* Wqh = (ushort*)(ws + 56 * MB);  // 56-66 dead after qkv
  ushort* Wql = (ushort*)(ws + 58 * MB);
  ushort* Wkh = (ushort*)(ws + 60 * MB);
  ushort* Wkl = (ushort*)(ws + 62 * MB);
  ushort* Wvh = (ushort*)(ws + 64 * MB);
  float*  S   = (float*)(ws + 40 * MB);   // 40-104 (over dead X/W)
  float*  Pt0 = (float*)(ws + 40 * MB);   // 40-56  pv partial 0 (S dead after smax)
  float*  Pt1 = (float*)(ws + 56 * MB);   // 56-72  pv partial 1
  float*  Out = (float*)d_out;

  const int n4 = NROWS * DDIM / 4;

  prep<<<4096, 256, 0, stream>>>(x, wq, wk, wv, Xh, Xl, Wqh, Wql, Wkh, Wkl, Wvh);
  gemm_qkv<<<dim3(24, 32), 256, 0, stream>>>(Xh, Xl, Wqh, Wql, Wkh, Wkl, Wvh,
                                             Qh, Ql, Kh, Kl, Vt);
  gemm_s<<<dim3(32, 32), 256, 0, stream>>>(Qh, Ql, Kh, Kl, S);
  softmax_pack<<<NROWS, 256, 0, stream>>>(S, Pp);
  gemm_pv<<<dim3(8, 32, 2), 256, 0, stream>>>(Pp, Vt, Pt0);
  add_partials<<<2048, 256, 0, stream>>>((const float4*)Pt0, (const float4*)Pt1,
                                         (float4*)Out, n4);
}